// Round 1
// baseline (1063.292 us; speedup 1.0000x reference)
//
#include <hip/hip_runtime.h>
#include <hip/hip_bf16.h>

typedef __attribute__((ext_vector_type(4))) float f32x4;
typedef __attribute__((ext_vector_type(8))) short bf16x8;
typedef __attribute__((ext_vector_type(4))) short s16x4;

#define LCOUNT 6

__device__ __forceinline__ unsigned short f2b(float f){
  __hip_bfloat16 h = __float2bfloat16(f);
  return __builtin_bit_cast(unsigned short, h);
}
__device__ __forceinline__ float b2f(unsigned short u){
  unsigned int x = ((unsigned int)u) << 16;
  return __builtin_bit_cast(float, x);
}

// ---------------- elementwise kernels ----------------
__global__ void k_cvt(const float* __restrict__ s, unsigned short* __restrict__ d, int n){
  int i = blockIdx.x*256 + threadIdx.x;
  if (i < n) d[i] = f2b(s[i]);
}

__global__ void k_embed(const float* __restrict__ data, const float* __restrict__ We,
                        const float* __restrict__ be, float* __restrict__ x,
                        unsigned short* __restrict__ xb){
  int idx = blockIdx.x*256 + threadIdx.x;   // 4,096,000 total
  int d = idx & 127, bn = idx >> 7;
  float v = data[bn*2]*We[d*2] + data[bn*2+1]*We[d*2+1] + be[d];
  x[idx] = v; xb[idx] = f2b(v);
}

// Zt layout: [b][col(256)][m(1024)] bf16. cols 0..127 hold v (then ek*v), 128..255 hold ek.
__global__ void k_prep(unsigned short* __restrict__ Zt){
  int idx = blockIdx.x*256 + threadIdx.x;   // 32*256*1024 = 8,388,608
  int m = idx & 1023;
  int c = (idx >> 10) & 255;
  if (m >= 1000){ Zt[idx] = 0; return; }
  if (c < 128){
    float v  = b2f(Zt[idx]);
    float ek = b2f(Zt[idx + (128<<10)]);
    Zt[idx] = f2b(ek * v);
  }
}

__global__ void k_post(float* __restrict__ x, const float* __restrict__ sigq,
                       const float* __restrict__ BD){
  int idx = blockIdx.x*256 + threadIdx.x;
  int d = idx & 127; size_t bn = (size_t)(idx >> 7);
  float bias = BD[bn*256 + d];
  float den  = BD[bn*256 + 128 + d];
  x[idx] += sigq[idx] * bias / den;
}

__global__ void k_stats(const float* __restrict__ x, float* __restrict__ part){
  int d = threadIdx.x, c = blockIdx.x, b = blockIdx.y;
  float s1 = 0.f, s2 = 0.f;
  int n0 = c*125;
  for (int n = n0; n < n0+125; ++n){
    float v = x[((size_t)b*1000 + n)*128 + d];
    s1 += v; s2 += v*v;
  }
  int o = ((b*8 + c)*128 + d)*2;
  part[o] = s1; part[o+1] = s2;
}

__global__ void k_fin(const float* __restrict__ part, const float* __restrict__ g,
                      const float* __restrict__ bta, float* __restrict__ na,
                      float* __restrict__ nc){
  int t = blockIdx.x*128 + threadIdx.x;  // 4096
  int b = t >> 7, d = t & 127;
  float s1 = 0.f, s2 = 0.f;
  for (int c = 0; c < 8; ++c){
    int o = ((b*8 + c)*128 + d)*2;
    s1 += part[o]; s2 += part[o+1];
  }
  float mean = s1 * 1e-3f;
  float var  = s2 * 1e-3f - mean*mean;
  float inv  = rsqrtf(var + 1e-5f);
  float a = g[d] * inv;
  na[t] = a; nc[t] = bta[d] - mean*a;
}

__global__ void k_apply(const float* __restrict__ src, const float* __restrict__ na,
                        const float* __restrict__ nc, float* __restrict__ dstf,
                        unsigned short* __restrict__ dstb, float* __restrict__ dout){
  int idx = blockIdx.x*256 + threadIdx.x;
  int d = idx & 127; int bn = idx >> 7; int b = bn/1000;
  int t = b*128 + d;
  float v = src[idx]*na[t] + nc[t];
  dstf[idx] = v; dstb[idx] = f2b(v);
  if (dout) dout[idx] = v;
}

// ---------------- weight GEMM (M=32000, BM=128, BN=128, BK=32) ----------------
// MODE 0: QKV — blockIdx.y selects q/k/v weight; q->sigmoid->f32, k->exp->Zt^T, v->Zt^T
// MODE 1: FF1 — bias + relu -> bf16 out [M][512]
// MODE 2: FF2 — bias + addsrc -> f32 out [M][128]
template<int MODE>
__global__ __launch_bounds__(256) void gemm_wt(
  const unsigned short* __restrict__ A,
  const unsigned short* __restrict__ Wq_,
  const unsigned short* __restrict__ Wk_,
  const unsigned short* __restrict__ Wv_,
  const float* __restrict__ bvec,
  float* __restrict__ out_f,
  unsigned short* __restrict__ out_b,
  const float* __restrict__ addsrc,
  int K)
{
  __shared__ unsigned short LA[128*40];
  __shared__ unsigned short LB[128*40];
  int tid = threadIdx.x;
  int wid = tid >> 6, lane = tid & 63;
  int wm = wid >> 1, wn = wid & 1;
  int m0 = blockIdx.x * 128;
  int yb = blockIdx.y;
  const unsigned short* W = Wq_;
  if (MODE == 0) W = (yb==0) ? Wq_ : ((yb==1) ? Wk_ : Wv_);
  int ncol0 = (MODE==0) ? 0 : (yb*128);

  f32x4 zf = {0.f,0.f,0.f,0.f};
  f32x4 acc[4][4];
#pragma unroll
  for (int i=0;i<4;i++)
#pragma unroll
    for (int j=0;j<4;j++) acc[i][j] = zf;

  int srow = tid >> 1, soff = (tid & 1) * 16;
  const unsigned short* Ap = A + (size_t)(m0 + srow)*K + soff;
  const unsigned short* Wp = W + (size_t)(ncol0 + srow)*K + soff;

  for (int k0 = 0; k0 < K; k0 += 32){
    f32x4 a0 = *(const f32x4*)(Ap + k0);
    f32x4 a1 = *(const f32x4*)(Ap + k0 + 8);
    f32x4 b0 = *(const f32x4*)(Wp + k0);
    f32x4 b1 = *(const f32x4*)(Wp + k0 + 8);
    *(f32x4*)&LA[srow*40 + soff]     = a0;
    *(f32x4*)&LA[srow*40 + soff + 8] = a1;
    *(f32x4*)&LB[srow*40 + soff]     = b0;
    *(f32x4*)&LB[srow*40 + soff + 8] = b1;
    __syncthreads();
    int l15 = lane & 15, ko = (lane >> 4) * 8;
    bf16x8 af[4], bfr[4];
#pragma unroll
    for (int i=0;i<4;i++) af[i]  = *(const bf16x8*)&LA[(wm*64 + i*16 + l15)*40 + ko];
#pragma unroll
    for (int j=0;j<4;j++) bfr[j] = *(const bf16x8*)&LB[(wn*64 + j*16 + l15)*40 + ko];
#pragma unroll
    for (int i=0;i<4;i++)
#pragma unroll
      for (int j=0;j<4;j++)
        acc[i][j] = __builtin_amdgcn_mfma_f32_16x16x32_bf16(af[i], bfr[j], acc[i][j], 0, 0, 0);
    __syncthreads();
  }

  int l15 = lane & 15, rbase = (lane >> 4) * 4;
#pragma unroll
  for (int i=0;i<4;i++){
    int grow0 = m0 + wm*64 + i*16 + rbase;
#pragma unroll
    for (int j=0;j<4;j++){
      int col = ncol0 + wn*64 + j*16 + l15;
      if (MODE == 0){
        if (yb == 0){
#pragma unroll
          for (int r=0;r<4;r++){
            float v = acc[i][j][r];
            out_f[(size_t)(grow0+r)*128 + col] = 1.f/(1.f + __expf(-v));
          }
        } else {
          int roff = (yb==1) ? (128 + col) : col;
          unsigned short u[4];
#pragma unroll
          for (int r=0;r<4;r++){
            float v = acc[i][j][r];
            u[r] = f2b((yb==1) ? __expf(v) : v);
          }
          int b0i = grow0 / 1000;
          int n0r = grow0 - b0i*1000;
          if (n0r <= 996){
            s16x4 pk = {(short)u[0],(short)u[1],(short)u[2],(short)u[3]};
            *(s16x4*)&out_b[((size_t)b0i*256 + roff)*1024 + n0r] = pk;
          } else {
#pragma unroll
            for (int r=0;r<4;r++){
              int gr = grow0 + r;
              int bb = gr/1000, nn = gr - bb*1000;
              out_b[((size_t)bb*256 + roff)*1024 + nn] = u[r];
            }
          }
        }
      } else if (MODE == 1){
        float bz = bvec[col];
#pragma unroll
        for (int r=0;r<4;r++){
          float v = acc[i][j][r] + bz;
          v = v > 0.f ? v : 0.f;
          out_b[(size_t)(grow0+r)*512 + col] = f2b(v);
        }
      } else {
        float bz = bvec[col];
#pragma unroll
        for (int r=0;r<4;r++){
          size_t idx = (size_t)(grow0+r)*128 + col;
          out_f[idx] = acc[i][j][r] + bz + addsrc[idx];
        }
      }
    }
  }
}

// ---------------- attention GEMM: BD[b] = exp(sc*dist[b]) @ Z[b]  ----------------
// BM=128 rows(n), BN=256 cols, BK=32 over m (padded to 1024, Zt pad rows are zero)
__global__ __launch_bounds__(512) void attn_gemm(
  const float* __restrict__ dist, const unsigned short* __restrict__ Zt,
  float* __restrict__ BD, const float* __restrict__ log_scale,
  const float* __restrict__ alpha, int layer)
{
  __shared__ unsigned short LA[128*40];
  __shared__ unsigned short LB[256*40];
  int tid = threadIdx.x;
  int wid = tid >> 6, lane = tid & 63;
  int wm = wid >> 2, wn = wid & 3;
  int bb = blockIdx.y;
  int n0 = blockIdx.x * 128;
  float sc = log_scale[0] * alpha[layer];
  const float* db = dist + (size_t)bb * 1000000;
  const unsigned short* Zb = Zt + ((size_t)bb << 18);

  f32x4 zf = {0.f,0.f,0.f,0.f};
  f32x4 acc[4][4];
#pragma unroll
  for (int i=0;i<4;i++)
#pragma unroll
    for (int j=0;j<4;j++) acc[i][j] = zf;

  int arow = tid >> 2, aq = (tid & 3) * 8;
  int an = n0 + arow; if (an > 999) an = 999;
  int bcol = tid >> 1, bh = (tid & 1) * 16;
  const size_t zbase = ((size_t)bcol << 10);

  for (int kk = 0; kk < 32; ++kk){
    int k0 = kk * 32;
    // stage A: exp(sc*dist) tile [128][32] -> bf16
    bf16x8 av;
    if (k0 + 32 <= 1000){
      const float* p = db + (size_t)an*1000 + k0 + aq;
      f32x4 v0 = *(const f32x4*)p;
      f32x4 v1 = *(const f32x4*)(p + 4);
#pragma unroll
      for (int e=0;e<4;e++){
        av[e]   = (short)f2b(__expf(sc * v0[e]));
        av[4+e] = (short)f2b(__expf(sc * v1[e]));
      }
    } else {
#pragma unroll
      for (int e=0;e<8;e++){
        int m = k0 + aq + e; if (m > 999) m = 999;
        av[e] = (short)f2b(__expf(sc * db[(size_t)an*1000 + m]));
      }
    }
    *(bf16x8*)&LA[arow*40 + aq] = av;
    // stage B: Zt tile [256 cols][32 m]
    const f32x4* zp = (const f32x4*)(Zb + zbase + k0 + bh);
    f32x4 z0 = zp[0], z1 = zp[1];
    *(f32x4*)&LB[bcol*40 + bh]     = z0;
    *(f32x4*)&LB[bcol*40 + bh + 8] = z1;
    __syncthreads();
    int l15 = lane & 15, ko = (lane >> 4) * 8;
    bf16x8 af[4], bfr[4];
#pragma unroll
    for (int i=0;i<4;i++) af[i]  = *(const bf16x8*)&LA[(wm*64 + i*16 + l15)*40 + ko];
#pragma unroll
    for (int j=0;j<4;j++) bfr[j] = *(const bf16x8*)&LB[(wn*64 + j*16 + l15)*40 + ko];
#pragma unroll
    for (int i=0;i<4;i++)
#pragma unroll
      for (int j=0;j<4;j++)
        acc[i][j] = __builtin_amdgcn_mfma_f32_16x16x32_bf16(af[i], bfr[j], acc[i][j], 0, 0, 0);
    __syncthreads();
  }

  int l15 = lane & 15, rbase = (lane >> 4) * 4;
#pragma unroll
  for (int i=0;i<4;i++){
    int nrow0 = n0 + wm*64 + i*16 + rbase;
#pragma unroll
    for (int j=0;j<4;j++){
      int col = wn*64 + j*16 + l15;
#pragma unroll
      for (int r=0;r<4;r++){
        int nr = nrow0 + r;
        if (nr < 1000)
          BD[((size_t)bb*1000 + nr)*256 + col] = acc[i][j][r];
      }
    }
  }
}

extern "C" void kernel_launch(void* const* d_in, const int* in_sizes, int n_in,
                              void* d_out, int out_size, void* d_ws, size_t ws_size,
                              hipStream_t stream) {
  const float* data = (const float*)d_in[0];
  const float* dist = (const float*)d_in[1];
  const float* log_scale = (const float*)d_in[2];
  const float* We = (const float*)d_in[3];
  const float* be = (const float*)d_in[4];
  const float* Wq = (const float*)d_in[5];
  const float* Wk = (const float*)d_in[6];
  const float* Wv = (const float*)d_in[7];
  const float* g1 = (const float*)d_in[8];
  const float* b1 = (const float*)d_in[9];
  const float* W1 = (const float*)d_in[10];
  const float* bw1 = (const float*)d_in[11];
  const float* W2 = (const float*)d_in[12];
  const float* bw2 = (const float*)d_in[13];
  const float* g2 = (const float*)d_in[14];
  const float* b2 = (const float*)d_in[15];
  const float* alpha = (const float*)d_in[16];
  float* dout = (float*)d_out;

  char* ws = (char*)d_ws;
  size_t off = 0;
  auto alloc = [&](size_t bytes) -> void* {
    void* p = ws + off; off += (bytes + 255) & ~(size_t)255; return p;
  };
  unsigned short* xb  = (unsigned short*)alloc(8192000);    // [32000][128] bf16
  float* x            = (float*)alloc(16384000);            // [32000][128] f32
  float* sigq         = (float*)alloc(16384000);            // [32000][128] f32
  unsigned short* Zt  = (unsigned short*)alloc(16777216);   // [32][256][1024] bf16
  void* bdh1          = alloc(32768000);                    // BD f32 [32000][256] | h1 bf16 [32000][512]
  float* BD           = (float*)bdh1;
  unsigned short* h1  = (unsigned short*)bdh1;
  float* x1           = (float*)alloc(16384000);
  unsigned short* x1b = (unsigned short*)alloc(8192000);
  float* part         = (float*)alloc(262144);              // [32][8][128][2]
  float* na           = (float*)alloc(16384);
  float* nc           = (float*)alloc(16384);
  unsigned short* wqb = (unsigned short*)alloc(196608);
  unsigned short* wkb = (unsigned short*)alloc(196608);
  unsigned short* wvb = (unsigned short*)alloc(196608);
  unsigned short* w1b = (unsigned short*)alloc(786432);
  unsigned short* w2b = (unsigned short*)alloc(786432);
  if (off > ws_size) return;  // workspace too small — bail (output stays wrong)

  // weight conversion f32 -> bf16
  k_cvt<<<(98304+255)/256, 256, 0, stream>>>(Wq, wqb, 98304);
  k_cvt<<<(98304+255)/256, 256, 0, stream>>>(Wk, wkb, 98304);
  k_cvt<<<(98304+255)/256, 256, 0, stream>>>(Wv, wvb, 98304);
  k_cvt<<<(393216+255)/256, 256, 0, stream>>>(W1, w1b, 393216);
  k_cvt<<<(393216+255)/256, 256, 0, stream>>>(W2, w2b, 393216);

  k_embed<<<16000, 256, 0, stream>>>(data, We, be, x, xb);

  for (int i = 0; i < LCOUNT; ++i){
    gemm_wt<0><<<dim3(250,3), 256, 0, stream>>>(xb, wqb + i*16384, wkb + i*16384, wvb + i*16384,
                                                nullptr, sigq, Zt, nullptr, 128);
    k_prep<<<32768, 256, 0, stream>>>(Zt);
    attn_gemm<<<dim3(8,32), 512, 0, stream>>>(dist, Zt, BD, log_scale, alpha, i);
    k_post<<<16000, 256, 0, stream>>>(x, sigq, BD);
    k_stats<<<dim3(8,32), 128, 0, stream>>>(x, part);
    k_fin<<<32, 128, 0, stream>>>(part, g1 + i*128, b1 + i*128, na, nc);
    k_apply<<<16000, 256, 0, stream>>>(x, na, nc, x1, x1b, nullptr);
    gemm_wt<1><<<dim3(250,4), 256, 0, stream>>>(x1b, w1b + i*65536, nullptr, nullptr,
                                                bw1 + i*512, nullptr, h1, nullptr, 128);
    gemm_wt<2><<<dim3(250,1), 256, 0, stream>>>(h1, w2b + i*65536, nullptr, nullptr,
                                                bw2 + i*128, x, nullptr, x1, 512);
    k_stats<<<dim3(8,32), 128, 0, stream>>>(x, part);
    k_fin<<<32, 128, 0, stream>>>(part, g2 + i*128, b2 + i*128, na, nc);
    k_apply<<<16000, 256, 0, stream>>>(x, na, nc, x, xb, (i == LCOUNT-1) ? dout : nullptr);
  }
}